// Round 6
// baseline (152.418 us; speedup 1.0000x reference)
//
#include <hip/hip_runtime.h>
#include <math.h>

// ClassMamba collapses: output = [upd_cls, patch(unchanged)].
// upd_cls depends only on token 0 (causal conv + scan from h0=0); A_log dead.
// Round 6: 4 stage kernels (was 5) — x_proj inlined redundantly into k4's 16
// chain blocks (256 KB weight/block via L3, cheaper than a launch boundary).
// Each stage spreads weights across blocks, dots vs ALL 4 batch vectors.
// 67 MB copy sliced 4 ways (one batch per kernel), overlapped with chain.

#define B_SZ 4
#define DIM 512
#define D_INNER 1024
#define L_TOK 4097
#define TOK_STRIDE (L_TOK * DIM)
#define PB4 (TOK_STRIDE / 4)       // 524416 float4 per batch
#define DT_RANK 32
#define D_STATE 16
#define CB 2040                    // copy blocks per kernel

// copy slice boundaries (float4 indices) — one batch per kernel
#define SL0 0u
#define SL1 ((unsigned)PB4)
#define SL2 (2u * PB4)
#define SL3 (3u * PB4)
#define SL4 (4u * PB4)

__device__ __forceinline__ float silu_f(float v) { return v / (1.f + expf(-v)); }
__device__ __forceinline__ float f4dot(float4 a, float4 b) {
    return a.x * b.x + a.y * b.y + a.z * b.z + a.w * b.w;
}
__device__ __forceinline__ float red16(float v) {
    v += __shfl_xor(v, 1, 64); v += __shfl_xor(v, 2, 64);
    v += __shfl_xor(v, 4, 64); v += __shfl_xor(v, 8, 64);
    return v;
}
__device__ __forceinline__ float red32(float v) {
    v = red16(v); v += __shfl_xor(v, 16, 64); return v;
}
__device__ __forceinline__ float sel4(int c, float a0, float a1, float a2, float a3) {
    return (c == 0) ? a0 : (c == 1) ? a1 : (c == 2) ? a2 : a3;
}

// copy slice [beg,end) of out[:] = x[:], skipping the 4 cls rows
__device__ __forceinline__ void do_copy(const float4* __restrict__ x4,
                                        float4* __restrict__ o4,
                                        int cb_idx, unsigned beg, unsigned end) {
    const unsigned stride = (unsigned)CB * 256u;
    for (unsigned i = beg + (unsigned)cb_idx * 256u + threadIdx.x; i < end; i += stride) {
        unsigned r = i;
        if (r >= 2u * PB4) r -= 2u * PB4;
        if (r >= (unsigned)PB4) r -= (unsigned)PB4;
        if (r >= 128u) o4[i] = x4[i];
    }
}

// ---- k1: q[b,r] = dot(cls[b], q_w[r,:])   8 chain blocks ----
__global__ void __launch_bounds__(256)
k1_q(const float* __restrict__ x, const float* __restrict__ q_w,
     float* __restrict__ q_ws, float4* __restrict__ o4) {
    const int blk = blockIdx.x, tid = threadIdx.x;
    if (blk >= 8) { do_copy((const float4*)x, o4, blk - 8, SL0, SL1); return; }
    __shared__ float cls[4 * DIM];
    {
        float4* cl4 = (float4*)cls;
        const float4* xg = (const float4*)x;
#pragma unroll
        for (int t = 0; t < 2; ++t) {
            int f = tid + t * 256;                 // 0..511
            cl4[f] = xg[(size_t)(f >> 7) * PB4 + (f & 127)];
        }
    }
    __syncthreads();
    const int w = tid >> 6, lane = tid & 63, c = lane & 15, g = lane >> 4;
#pragma unroll
    for (int p = 0; p < 4; ++p) {
        int r = blk * 64 + w * 16 + p * 4 + g;
        const float4* wr = (const float4*)(q_w + (size_t)r * DIM);
        float a0 = 0, a1 = 0, a2 = 0, a3 = 0;
#pragma unroll
        for (int j = 0; j < 8; ++j) {
            float4 wv = wr[c + 16 * j];
            a0 += f4dot(wv, ((const float4*)(cls))[c + 16 * j]);
            a1 += f4dot(wv, ((const float4*)(cls + DIM))[c + 16 * j]);
            a2 += f4dot(wv, ((const float4*)(cls + 2 * DIM))[c + 16 * j]);
            a3 += f4dot(wv, ((const float4*)(cls + 3 * DIM))[c + 16 * j]);
        }
        a0 = red16(a0); a1 = red16(a1); a2 = red16(a2); a3 = red16(a3);
        if (c < 4) q_ws[c * DIM + r] = sel4(c, a0, a1, a2, a3);
    }
}

// ---- k2: raw[b,r] = dot(q[b], in_proj_w[r,:]); conv tap + silu   32 blocks ----
__global__ void __launch_bounds__(256)
k2_xz(const float* __restrict__ q_ws, const float* __restrict__ in_proj_w,
      const float* __restrict__ conv_w, const float* __restrict__ conv_b,
      float* __restrict__ xs_ws, float* __restrict__ gz_ws,
      const float4* __restrict__ x4, float4* __restrict__ o4) {
    const int blk = blockIdx.x, tid = threadIdx.x;
    if (blk >= 32) { do_copy(x4, o4, blk - 32, SL1, SL2); return; }
    __shared__ float q_lds[4 * DIM];
    {
        float4* ql = (float4*)q_lds;
        const float4* qg = (const float4*)q_ws;
        ql[tid] = qg[tid]; ql[tid + 256] = qg[tid + 256];
    }
    __syncthreads();
    const int w = tid >> 6, lane = tid & 63, c = lane & 15, g = lane >> 4;
#pragma unroll
    for (int p = 0; p < 4; ++p) {
        int r = blk * 64 + w * 16 + p * 4 + g;   // 0..2047
        const float4* wr = (const float4*)(in_proj_w + (size_t)r * DIM);
        float a0 = 0, a1 = 0, a2 = 0, a3 = 0;
#pragma unroll
        for (int j = 0; j < 8; ++j) {
            float4 wv = wr[c + 16 * j];
            a0 += f4dot(wv, ((const float4*)(q_lds))[c + 16 * j]);
            a1 += f4dot(wv, ((const float4*)(q_lds + DIM))[c + 16 * j]);
            a2 += f4dot(wv, ((const float4*)(q_lds + 2 * DIM))[c + 16 * j]);
            a3 += f4dot(wv, ((const float4*)(q_lds + 3 * DIM))[c + 16 * j]);
        }
        a0 = red16(a0); a1 = red16(a1); a2 = red16(a2); a3 = red16(a3);
        if (c < 4) {
            float v = sel4(c, a0, a1, a2, a3);
            if (r < D_INNER)
                xs_ws[c * D_INNER + r] = silu_f(v * conv_w[r * 4 + 3] + conv_b[r]);
            else
                gz_ws[c * D_INNER + (r - D_INNER)] = silu_f(v);
        }
    }
}

// ---- k4: inline x_proj (redundant/block) + delta/scan@t0/gate -> y,
//          then o[b,r] = dot(y[b], out_proj_w[r,:])   16 chain blocks ----
__global__ void __launch_bounds__(256)
k4_out(const float* __restrict__ xs_ws, const float* __restrict__ gz_ws,
       const float* __restrict__ x_proj_w, const float* __restrict__ dt_w,
       const float* __restrict__ dt_b, const float* __restrict__ Dp,
       const float* __restrict__ out_proj_w, float* __restrict__ o_ws,
       const float4* __restrict__ x4, float4* __restrict__ o4) {
    const int blk = blockIdx.x, tid = threadIdx.x;
    if (blk >= 16) { do_copy(x4, o4, blk - 16, SL2, SL3); return; }
    __shared__ float xs_lds[4 * D_INNER];   // 16 KB
    __shared__ float xd_lds[4 * 64];        // 1 KB
    __shared__ float y_lds[4 * D_INNER];    // 16 KB
    {
        float4* xl = (float4*)xs_lds;
        const float4* xg = (const float4*)xs_ws;
#pragma unroll
        for (int t = 0; t < 4; ++t) xl[tid + t * 256] = xg[tid + t * 256];
    }
    __syncthreads();
    const int w = tid >> 6, lane = tid & 63, c2 = lane & 31, g2 = lane >> 5;

    // inline x_proj: 64 rows x 4 batches; 8 rows per pass (4 waves x 2 groups)
#pragma unroll
    for (int p = 0; p < 8; ++p) {
        int r = p * 8 + w * 2 + g2;   // 0..63
        const float4* wr = (const float4*)(x_proj_w + (size_t)r * D_INNER);
        float a0 = 0, a1 = 0, a2 = 0, a3 = 0;
#pragma unroll
        for (int j = 0; j < 8; ++j) {
            float4 wv = wr[c2 + 32 * j];
            a0 += f4dot(wv, ((const float4*)(xs_lds))[c2 + 32 * j]);
            a1 += f4dot(wv, ((const float4*)(xs_lds + D_INNER))[c2 + 32 * j]);
            a2 += f4dot(wv, ((const float4*)(xs_lds + 2 * D_INNER))[c2 + 32 * j]);
            a3 += f4dot(wv, ((const float4*)(xs_lds + 3 * D_INNER))[c2 + 32 * j]);
        }
        a0 = red32(a0); a1 = red32(a1); a2 = red32(a2); a3 = red32(a3);
        if (c2 < 4) xd_lds[c2 * 64 + r] = sel4(c2, a0, a1, a2, a3);
    }
    __syncthreads();

    // delta + scan@t0 + gate -> y
    float S[4];
#pragma unroll
    for (int b = 0; b < 4; ++b) {
        float s = 0.f;
#pragma unroll
        for (int n = 0; n < D_STATE; ++n)
            s += xd_lds[b * 64 + 32 + n] * xd_lds[b * 64 + 48 + n];
        S[b] = s;
    }
#pragma unroll
    for (int qq = 0; qq < 4; ++qq) {
        int d = tid + qq * 256;
        const float4* dw = (const float4*)(dt_w + (size_t)d * DT_RANK);
        float4 dwv[8];
#pragma unroll
        for (int j = 0; j < 8; ++j) dwv[j] = dw[j];
        float Dd = Dp[d], db = dt_b[d];
#pragma unroll
        for (int b = 0; b < 4; ++b) {
            const float4* xd4 = (const float4*)(xd_lds + b * 64);
            float dp = db;
#pragma unroll
            for (int j = 0; j < 8; ++j) dp += f4dot(dwv[j], xd4[j]);
            float delta = (dp > 20.f) ? dp : log1pf(expf(dp));
            y_lds[b * D_INNER + d] =
                xs_lds[b * D_INNER + d] * (delta * S[b] + Dd) * gz_ws[b * D_INNER + d];
        }
    }
    __syncthreads();

    // out_proj: 32 rows per block
#pragma unroll
    for (int p = 0; p < 4; ++p) {
        int r = blk * 32 + w * 8 + p * 2 + g2;   // 0..511
        const float4* wr = (const float4*)(out_proj_w + (size_t)r * D_INNER);
        float a0 = 0, a1 = 0, a2 = 0, a3 = 0;
#pragma unroll
        for (int j = 0; j < 8; ++j) {
            float4 wv = wr[c2 + 32 * j];
            a0 += f4dot(wv, ((const float4*)(y_lds))[c2 + 32 * j]);
            a1 += f4dot(wv, ((const float4*)(y_lds + D_INNER))[c2 + 32 * j]);
            a2 += f4dot(wv, ((const float4*)(y_lds + 2 * D_INNER))[c2 + 32 * j]);
            a3 += f4dot(wv, ((const float4*)(y_lds + 3 * D_INNER))[c2 + 32 * j]);
        }
        a0 = red32(a0); a1 = red32(a1); a2 = red32(a2); a3 = red32(a3);
        if (c2 < 4) o_ws[c2 * DIM + r] = sel4(c2, a0, a1, a2, a3);
    }
}

// ---- k5: upd[b,r] = dot(o[b], proj_w[r,:]) + proj_b[r] -> out token 0   8 blocks ----
__global__ void __launch_bounds__(256)
k5_upd(const float* __restrict__ o_ws, const float* __restrict__ proj_w,
       const float* __restrict__ proj_b, float* __restrict__ out,
       const float4* __restrict__ x4, float4* __restrict__ o4) {
    const int blk = blockIdx.x, tid = threadIdx.x;
    if (blk >= 8) { do_copy(x4, o4, blk - 8, SL3, SL4); return; }
    __shared__ float o_lds[4 * DIM];
    {
        float4* ol = (float4*)o_lds;
        const float4* og = (const float4*)o_ws;
        ol[tid] = og[tid]; ol[tid + 256] = og[tid + 256];
    }
    __syncthreads();
    const int w = tid >> 6, lane = tid & 63, c = lane & 15, g = lane >> 4;
#pragma unroll
    for (int p = 0; p < 4; ++p) {
        int r = blk * 64 + w * 16 + p * 4 + g;
        const float4* wr = (const float4*)(proj_w + (size_t)r * DIM);
        float a0 = 0, a1 = 0, a2 = 0, a3 = 0;
#pragma unroll
        for (int j = 0; j < 8; ++j) {
            float4 wv = wr[c + 16 * j];
            a0 += f4dot(wv, ((const float4*)(o_lds))[c + 16 * j]);
            a1 += f4dot(wv, ((const float4*)(o_lds + DIM))[c + 16 * j]);
            a2 += f4dot(wv, ((const float4*)(o_lds + 2 * DIM))[c + 16 * j]);
            a3 += f4dot(wv, ((const float4*)(o_lds + 3 * DIM))[c + 16 * j]);
        }
        a0 = red16(a0); a1 = red16(a1); a2 = red16(a2); a3 = red16(a3);
        if (c < 4) out[(size_t)c * TOK_STRIDE + r] = sel4(c, a0, a1, a2, a3) + proj_b[r];
    }
}

extern "C" void kernel_launch(void* const* d_in, const int* in_sizes, int n_in,
                              void* d_out, int out_size, void* d_ws, size_t ws_size,
                              hipStream_t stream) {
    const float* x          = (const float*)d_in[0];
    const float* q_w        = (const float*)d_in[1];
    const float* in_proj_w  = (const float*)d_in[2];
    const float* conv_w     = (const float*)d_in[3];
    const float* conv_b     = (const float*)d_in[4];
    const float* x_proj_w   = (const float*)d_in[5];
    const float* dt_w       = (const float*)d_in[6];
    const float* dt_b       = (const float*)d_in[7];
    // d_in[8] = A_log: unused (h0 = 0)
    const float* Dp         = (const float*)d_in[9];
    const float* out_proj_w = (const float*)d_in[10];
    const float* proj_w     = (const float*)d_in[11];
    const float* proj_b     = (const float*)d_in[12];
    float* out = (float*)d_out;
    float* ws  = (float*)d_ws;

    float* q_ws  = ws;          // 2048
    float* xs_ws = ws + 2048;   // 4096
    float* gz_ws = ws + 6144;   // 4096
    float* o_ws  = ws + 10240;  // 2048

    const float4* x4 = (const float4*)x;
    float4* o4 = (float4*)out;

    k1_q  <<<8 + CB,  256, 0, stream>>>(x, q_w, q_ws, o4);
    k2_xz <<<32 + CB, 256, 0, stream>>>(q_ws, in_proj_w, conv_w, conv_b,
                                        xs_ws, gz_ws, x4, o4);
    k4_out<<<16 + CB, 256, 0, stream>>>(xs_ws, gz_ws, x_proj_w, dt_w, dt_b, Dp,
                                        out_proj_w, o_ws, x4, o4);
    k5_upd<<<8 + CB,  256, 0, stream>>>(o_ws, proj_w, proj_b, out, x4, o4);
}

// Round 7
// 140.800 us; speedup vs baseline: 1.0825x; 1.0825x over previous
//
#include <hip/hip_runtime.h>
#include <math.h>

// ClassMamba collapses: output = [upd_cls, patch(unchanged)].
// upd_cls depends only on token 0 (causal conv + scan from h0=0); A_log dead.
// Round 7: 3 kernels via PARTIAL-SUM fusion (column-sliced next-stage weights,
// zero redundant full reads):
//  K_A: q rows seg (16/block) + in_proj col-partials      (32 chain blocks)
//  K_B: sum raw -> conv/silu -> xs,gz + x_proj partials   (32 chain blocks)
//  K_C: sum xd -> delta/scan/gate -> y -> out_proj rows seg
//       -> proj col-partials (atomicAdd) -> ticket; last block: bias + write
// 67 MB copy sliced 40/35/25 across the 3 kernels.

#define B_SZ 4
#define DIM 512
#define D_INNER 1024
#define L_TOK 4097
#define TOK_STRIDE (L_TOK * DIM)
#define PB4 (TOK_STRIDE / 4)       // 524416 float4 per batch
#define DT_RANK 32
#define D_STATE 16
#define NCH 32
#define NB 2048
#define NCP (NB - NCH)

// ws offsets (floats)
#define OFF_PRAW 0          // [32][2048][4] = 262144
#define OFF_XS   262144     // [4][1024]
#define OFF_GZ   266240     // [4][1024]
#define OFF_PXD  270336     // [16][64][4] = 4096
#define OFF_ACC  274432     // [4][512]  = 2048
#define OFF_TKT  276480     // 1 unsigned

// copy slice boundaries (float4 indices)
#define SL0 0u
#define SL1 839066u
#define SL2 1573248u
#define SL3 2097664u

__device__ __forceinline__ float silu_f(float v) { return v / (1.f + expf(-v)); }
__device__ __forceinline__ float f4dot(float4 a, float4 b) {
    return a.x * b.x + a.y * b.y + a.z * b.z + a.w * b.w;
}
__device__ __forceinline__ float red32(float v) {
    v += __shfl_xor(v, 1, 64); v += __shfl_xor(v, 2, 64);
    v += __shfl_xor(v, 4, 64); v += __shfl_xor(v, 8, 64);
    v += __shfl_xor(v, 16, 64);
    return v;
}
__device__ __forceinline__ float sel4(int c, float a0, float a1, float a2, float a3) {
    return (c == 0) ? a0 : (c == 1) ? a1 : (c == 2) ? a2 : a3;
}

__device__ __forceinline__ void do_copy(const float4* __restrict__ x4,
                                        float4* __restrict__ o4,
                                        int cb_idx, unsigned beg, unsigned end) {
    const unsigned stride = (unsigned)NCP * 256u;
    for (unsigned i = beg + (unsigned)cb_idx * 256u + threadIdx.x; i < end; i += stride) {
        unsigned r = i;
        if (r >= 2u * PB4) r -= 2u * PB4;
        if (r >= (unsigned)PB4) r -= (unsigned)PB4;
        if (r >= 128u) o4[i] = x4[i];   // skip the 4 cls rows (written by K_C)
    }
}

// ---- K_A: q rows [16*blk,+16) + in_proj column-partials ----
__global__ void __launch_bounds__(256)
kA(const float* __restrict__ x, const float* __restrict__ q_w,
   const float* __restrict__ in_proj_w, float* __restrict__ ws,
   float4* __restrict__ o4) {
    const int blk = blockIdx.x, tid = threadIdx.x;
    if (blk >= NCH) { do_copy((const float4*)x, o4, blk - NCH, SL0, SL1); return; }
    __shared__ __align__(16) float cls[4 * DIM];
    __shared__ __align__(16) float qseg[4 * 16];
    {
        float4* c4 = (float4*)cls;
        const float4* x4 = (const float4*)x;
#pragma unroll
        for (int it = 0; it < 2; ++it) {
            int f = tid + it * 256;                   // 0..511
            c4[f] = x4[(size_t)(f >> 7) * PB4 + (f & 127)];
        }
    }
    __syncthreads();
    {   // q_seg: row=tid>>4, b=(tid>>2)&3, part=tid&3 (k-range part*128..+128)
        int row = tid >> 4, b = (tid >> 2) & 3, part = tid & 3;
        const float4* w = (const float4*)(q_w + (size_t)(blk * 16 + row) * DIM) + part * 32;
        const float4* c = (const float4*)(cls + b * DIM) + part * 32;
        float v = 0.f;
#pragma unroll
        for (int m = 0; m < 32; ++m) v += f4dot(w[m], c[m]);
        v += __shfl_xor(v, 1, 64);
        v += __shfl_xor(v, 2, 64);
        if (part == 0) qseg[b * 16 + row] = v;
    }
    __syncthreads();
    // in_proj partial: all 2048 rows, cols [16*blk, +16)
    float* praw = ws + OFF_PRAW + blk * 8192;
#pragma unroll
    for (int rr = 0; rr < 8; ++rr) {
        int r = tid + 256 * rr;
        const float4* w = (const float4*)(in_proj_w + (size_t)r * DIM + blk * 16);
        float4 w0 = w[0], w1 = w[1], w2 = w[2], w3 = w[3];
#pragma unroll
        for (int b = 0; b < 4; ++b) {
            const float4* q4 = (const float4*)(qseg + b * 16);
            praw[r * 4 + b] = f4dot(w0, q4[0]) + f4dot(w1, q4[1]) +
                              f4dot(w2, q4[2]) + f4dot(w3, q4[3]);
        }
    }
}

// ---- K_B: sum raw seg -> conv/silu -> xs,gz; x_proj column-partials ----
__global__ void __launch_bounds__(256)
kB(const float* __restrict__ conv_w, const float* __restrict__ conv_b,
   const float* __restrict__ x_proj_w, float* __restrict__ ws,
   const float4* __restrict__ x4, float4* __restrict__ o4) {
    const int blk = blockIdx.x, tid = threadIdx.x;
    if (blk >= NCH) { do_copy(x4, o4, blk - NCH, SL1, SL2); return; }
    __shared__ __align__(16) float seg[4][64];   // this block's 64 rows (xs or gz)
    {
        int rr = tid >> 2, b = tid & 3;
        int g = blk * 64 + rr;                   // raw row 0..2047
        float acc = 0.f;
        const float* p = ws + OFF_PRAW + g * 4 + b;
#pragma unroll 8
        for (int s = 0; s < 32; ++s) acc += p[s * 8192];
        float v = (g < D_INNER) ? silu_f(acc * conv_w[g * 4 + 3] + conv_b[g])
                                : silu_f(acc);
        seg[b][rr] = v;
        if (g < D_INNER) ws[OFF_XS + b * D_INNER + g] = v;
        else             ws[OFF_GZ + b * D_INNER + (g - D_INNER)] = v;
    }
    if (blk == 31) {   // zero the proj accumulator + ticket for K_C
        for (int m = tid; m < 2048; m += 256) ws[OFF_ACC + m] = 0.f;
        if (tid == 0) ((unsigned*)(ws + OFF_TKT))[0] = 0u;
    }
    __syncthreads();
    if (blk < 16) {    // x_proj partial: 64 xd rows, cols [64*blk, +64)
        int row = tid >> 2, b = tid & 3;
        const float4* w = (const float4*)(x_proj_w + (size_t)row * D_INNER + blk * 64);
        const float4* xv = (const float4*)(&seg[b][0]);
        float v = 0.f;
#pragma unroll
        for (int m = 0; m < 16; ++m) v += f4dot(w[m], xv[m]);
        ws[OFF_PXD + blk * 256 + row * 4 + b] = v;
    }
}

// ---- K_C: sum xd -> delta/scan/gate -> y -> out_proj rows -> proj partials ----
__global__ void __launch_bounds__(256)
kC(const float* __restrict__ dt_w, const float* __restrict__ dt_b,
   const float* __restrict__ Dp, const float* __restrict__ out_proj_w,
   const float* __restrict__ proj_w, const float* __restrict__ proj_b,
   float* __restrict__ ws, float* __restrict__ out,
   const float4* __restrict__ x4, float4* __restrict__ o4) {
    const int blk = blockIdx.x, tid = threadIdx.x;
    if (blk >= NCH) { do_copy(x4, o4, blk - NCH, SL2, SL3); return; }
    __shared__ __align__(16) float xd[4][64];
    __shared__ __align__(16) float y[4][D_INNER];
    __shared__ __align__(16) float oseg[4][16];
    __shared__ unsigned lastflag;
    {   // sum 16 xd partial sets
        int r = tid >> 2, b = tid & 3;
        float acc = 0.f;
        const float* p = ws + OFF_PXD + r * 4 + b;
#pragma unroll
        for (int s = 0; s < 16; ++s) acc += p[s * 256];
        xd[b][r] = acc;
    }
    __syncthreads();
    float S[4];
#pragma unroll
    for (int b = 0; b < 4; ++b) {
        float s = 0.f;
#pragma unroll
        for (int n = 0; n < D_STATE; ++n) s += xd[b][32 + n] * xd[b][48 + n];
        S[b] = s;
    }
#pragma unroll
    for (int qq = 0; qq < 4; ++qq) {   // y for d = tid + 256*qq
        int d = tid + qq * 256;
        const float4* dw = (const float4*)(dt_w + (size_t)d * DT_RANK);
        float4 dv[8];
#pragma unroll
        for (int j = 0; j < 8; ++j) dv[j] = dw[j];
        float Dd = Dp[d], db = dt_b[d];
#pragma unroll
        for (int b = 0; b < 4; ++b) {
            const float4* xd4 = (const float4*)(&xd[b][0]);
            float dp = db;
#pragma unroll
            for (int j = 0; j < 8; ++j) dp += f4dot(dv[j], xd4[j]);
            float delta = (dp > 20.f) ? dp : log1pf(expf(dp));
            y[b][d] = ws[OFF_XS + b * D_INNER + d] * (delta * S[b] + Dd)
                    * ws[OFF_GZ + b * D_INNER + d];
        }
    }
    __syncthreads();
    {   // out_proj rows [16*blk, +16): wave-reduced dots of 1024
        int w = tid >> 6, lane = tid & 63, c2 = lane & 31, g2 = lane >> 5;
#pragma unroll
        for (int p = 0; p < 2; ++p) {
            int rl = p * 8 + w * 2 + g2;          // 0..15
            int r = blk * 16 + rl;
            const float4* wr = (const float4*)(out_proj_w + (size_t)r * D_INNER);
            float a0 = 0, a1 = 0, a2 = 0, a3 = 0;
#pragma unroll
            for (int j = 0; j < 8; ++j) {
                float4 wv = wr[c2 + 32 * j];
                a0 += f4dot(wv, ((const float4*)&y[0][0])[c2 + 32 * j]);
                a1 += f4dot(wv, ((const float4*)&y[1][0])[c2 + 32 * j]);
                a2 += f4dot(wv, ((const float4*)&y[2][0])[c2 + 32 * j]);
                a3 += f4dot(wv, ((const float4*)&y[3][0])[c2 + 32 * j]);
            }
            a0 = red32(a0); a1 = red32(a1); a2 = red32(a2); a3 = red32(a3);
            if (c2 < 4) oseg[c2][rl] = sel4(c2, a0, a1, a2, a3);
        }
    }
    __syncthreads();
    {   // proj partial: all 512 rows, cols [16*blk, +16) -> atomicAdd
#pragma unroll
        for (int rr = 0; rr < 2; ++rr) {
            int r = tid * 2 + rr;
            const float4* w = (const float4*)(proj_w + (size_t)r * DIM + blk * 16);
            float4 w0 = w[0], w1 = w[1], w2 = w[2], w3 = w[3];
#pragma unroll
            for (int b = 0; b < 4; ++b) {
                const float4* ov = (const float4*)(&oseg[b][0]);
                float v = f4dot(w0, ov[0]) + f4dot(w1, ov[1]) +
                          f4dot(w2, ov[2]) + f4dot(w3, ov[3]);
                atomicAdd(ws + OFF_ACC + b * DIM + r, v);
            }
        }
    }
    __threadfence();
    __syncthreads();
    if (tid == 0) {
        unsigned old = atomicAdd((unsigned*)(ws + OFF_TKT), 1u);
        lastflag = (old == NCH - 1) ? 1u : 0u;
    }
    __syncthreads();
    if (lastflag) {
        __threadfence();
#pragma unroll
        for (int m = 0; m < 8; ++m) {
            int idx = tid + m * 256;              // 0..2047
            int b = idx >> 9, r = idx & 511;
            out[(size_t)b * TOK_STRIDE + r] = ws[OFF_ACC + b * DIM + r] + proj_b[r];
        }
    }
}

extern "C" void kernel_launch(void* const* d_in, const int* in_sizes, int n_in,
                              void* d_out, int out_size, void* d_ws, size_t ws_size,
                              hipStream_t stream) {
    const float* x          = (const float*)d_in[0];
    const float* q_w        = (const float*)d_in[1];
    const float* in_proj_w  = (const float*)d_in[2];
    const float* conv_w     = (const float*)d_in[3];
    const float* conv_b     = (const float*)d_in[4];
    const float* x_proj_w   = (const float*)d_in[5];
    const float* dt_w       = (const float*)d_in[6];
    const float* dt_b       = (const float*)d_in[7];
    // d_in[8] = A_log: unused (h0 = 0)
    const float* Dp         = (const float*)d_in[9];
    const float* out_proj_w = (const float*)d_in[10];
    const float* proj_w     = (const float*)d_in[11];
    const float* proj_b     = (const float*)d_in[12];
    float* out = (float*)d_out;
    float* ws  = (float*)d_ws;

    const float4* x4 = (const float4*)x;
    float4* o4 = (float4*)out;

    kA<<<NB, 256, 0, stream>>>(x, q_w, in_proj_w, ws, o4);
    kB<<<NB, 256, 0, stream>>>(conv_w, conv_b, x_proj_w, ws, x4, o4);
    kC<<<NB, 256, 0, stream>>>(dt_w, dt_b, Dp, out_proj_w, proj_w, proj_b,
                               ws, out, x4, o4);
}